// Round 13
// baseline (1293.469 us; speedup 1.0000x reference)
//
#include <hip/hip_runtime.h>

typedef __attribute__((ext_vector_type(8))) short short8;
typedef __attribute__((ext_vector_type(4))) float f32x4;
typedef __attribute__((ext_vector_type(4))) unsigned short us4v;
typedef unsigned short ushort_t;
typedef unsigned int uint_t;

#define BB 4
#define T_ 1024
#define T2 2048
#define DD 256
#define DIN 512
#define NMARK 64
#define LNEPS 1e-5f
#define KDIV (-0.035977892078032f)
#define SEGL 8

__device__ __forceinline__ ushort_t f2bf(float f) {
  unsigned int u = __float_as_uint(f);
  unsigned int r = (u + 0x7fffu + ((u >> 16) & 1u)) >> 16;
  return (ushort_t)r;
}
__device__ __forceinline__ uint_t pack2(float a, float b) {
  return (uint_t)f2bf(a) | ((uint_t)f2bf(b) << 16);
}
__device__ __forceinline__ uint_t cvtpk(float lo, float hi) {
  uint_t r;
  asm("v_cvt_pk_bf16_f32 %0, %1, %2" : "=v"(r) : "v"(lo), "v"(hi));
  return r;
}

typedef const __attribute__((address_space(1))) unsigned int* as1cu32;
typedef __attribute__((address_space(3))) unsigned int* as3u32;
__device__ __forceinline__ void async_copy16(const void* g, void* l) {
  __builtin_amdgcn_global_load_lds((as1cu32)g, (as3u32)l, 16, 0, 0);
}

// ---------- zero the per-chunk segment counters (once per call) ----------
__global__ __launch_bounds__(256) void k_zero(int* __restrict__ cnt) {
  cnt[threadIdx.x] = 0;
}

// ---------- init: type/time embeddings -> Xh (bf16), Cur = 0 ----------
__global__ __launch_bounds__(256) void k_init(const float* __restrict__ ev,
                                              const float* __restrict__ tm,
                                              const float* __restrict__ Wt,
                                              const float* __restrict__ bt,
                                              ushort_t* __restrict__ Xh,
                                              float* __restrict__ Cur) {
  const int btq = blockIdx.x;
  const int b = btq >> 10;
  const int t = btq & 1023;
  const int d = threadIdx.x;
  __shared__ float evs[NMARK];
  if (d < NMARK) evs[d] = ev[(size_t)btq * NMARK + d];
  __syncthreads();
  float s = bt[d];
#pragma unroll
  for (int m = 0; m < NMARK; ++m) s += evs[m] * Wt[m * DD + d];
  const float te_type = tanhf(s);
  const float tv = tm[btq];
  const int i = d >> 1;
  const float dv = expf((float)(2 * i) * KDIV);
  const float ang = tv * dv;
  const float te_time = (d & 1) ? cosf(ang) : sinf(ang);
  ushort_t* Xb = Xh + (size_t)b * T2 * DIN;
  const ushort_t tt = f2bf(te_time);
  Xb[(size_t)t * DIN + d] = f2bf(te_type);
  Xb[(size_t)t * DIN + DD + d] = tt;
  Xb[(size_t)(T_ + t) * DIN + d] = 0;
  Xb[(size_t)(T_ + t) * DIN + DD + d] = tt;
  Cur[((size_t)b * T_ + t) * DD + d] = 0.0f;
}

// ---------- weight transpose: W[hl][k][n] f32 -> WT[mat][n][k] bf16 ----------
__global__ __launch_bounds__(256) void k_transW(const float* __restrict__ Wq,
                                                const float* __restrict__ Wk,
                                                const float* __restrict__ Wv,
                                                ushort_t* __restrict__ WT) {
  const int mi = blockIdx.x;
  const int wsel = mi / 12, hl = mi % 12;
  const float* W = ((wsel == 0) ? Wq : (wsel == 1) ? Wk : Wv) + (size_t)hl * DIN * DD;
  const int t = blockIdx.y;
  const int k0 = (t >> 2) * 64, n0 = (t & 3) * 64;
  __shared__ float Ts[64][65];
  const int tid = threadIdx.x;
#pragma unroll
  for (int i = 0; i < 16; ++i) {
    const int idx = tid + i * 256;
    const int r = idx >> 6, c = idx & 63;
    Ts[r][c] = W[(size_t)(k0 + r) * DD + n0 + c];
  }
  __syncthreads();
  ushort_t* D = WT + (size_t)mi * DD * DIN;
#pragma unroll
  for (int i = 0; i < 16; ++i) {
    const int idx = tid + i * 256;
    const int rn = idx >> 6, ck = idx & 63;
    D[(size_t)(n0 + rn) * DIN + k0 + ck] = f2bf(Ts[ck][rn]);
  }
}

// ---------- QKV GEMM; V written pi32-permuted into 32-wide TILES ----------
// VTt[b][tile32(64)][d(256)][32] bf16: 16KB contiguous per KV-tile.
__global__ __launch_bounds__(256) void k_qkv(const ushort_t* __restrict__ Xh,
                                             const ushort_t* __restrict__ WT,
                                             const float* __restrict__ bq,
                                             const float* __restrict__ bk,
                                             const float* __restrict__ bv,
                                             ushort_t* __restrict__ Qh,
                                             ushort_t* __restrict__ Kh,
                                             ushort_t* __restrict__ VTt,
                                             int hl) {
  const int m0 = blockIdx.x * 128;
  const int n0 = blockIdx.y * 128;
  const int wsel = blockIdx.z;
  const ushort_t* Bt = WT + ((size_t)(wsel * 12 + hl)) * DD * DIN + (size_t)n0 * DIN;
  const float* bias = (wsel == 0) ? bq : (wsel == 1) ? bk : bv;

  __shared__ ushort_t As[128 * 64];
  __shared__ ushort_t Bs[128 * 64];
  const int tid = threadIdx.x;
  const int w = tid >> 6, lane = tid & 63;
  const int wr = w >> 1, wc = w & 1;
  const int lr = lane & 15, kg = lane >> 4;

  f32x4 acc[4][4];
  const f32x4 z4 = {0.f, 0.f, 0.f, 0.f};
#pragma unroll
  for (int a = 0; a < 4; ++a)
#pragma unroll
    for (int c = 0; c < 4; ++c) acc[a][c] = z4;

  for (int k0 = 0; k0 < DIN; k0 += 64) {
#pragma unroll
    for (int i = 0; i < 4; ++i) {
      const int idx = tid + i * 256;
      const int row = idx >> 3, ch = idx & 7;
      const int db = row * 128 + ((ch * 16) ^ ((row & 7) << 4));
      uint4 va = *(const uint4*)&Xh[(size_t)(m0 + row) * DIN + k0 + ch * 8];
      *(uint4*)((char*)As + db) = va;
      uint4 vb = *(const uint4*)&Bt[(size_t)row * DIN + k0 + ch * 8];
      *(uint4*)((char*)Bs + db) = vb;
    }
    __syncthreads();
#pragma unroll
    for (int kk = 0; kk < 2; ++kk) {
      short8 af[4], bfr[4];
      const int cb = kk * 64 + kg * 16;
#pragma unroll
      for (int mi = 0; mi < 4; ++mi) {
        const int row = wr * 64 + mi * 16 + lr;
        af[mi] = *(const short8*)((const char*)As + row * 128 + (cb ^ ((row & 7) << 4)));
      }
#pragma unroll
      for (int ni = 0; ni < 4; ++ni) {
        const int row = wc * 64 + ni * 16 + lr;
        bfr[ni] = *(const short8*)((const char*)Bs + row * 128 + (cb ^ ((row & 7) << 4)));
      }
#pragma unroll
      for (int mi = 0; mi < 4; ++mi)
#pragma unroll
        for (int ni = 0; ni < 4; ++ni)
          acc[mi][ni] = __builtin_amdgcn_mfma_f32_16x16x32_bf16(af[mi], bfr[ni], acc[mi][ni], 0, 0, 0);
    }
    __syncthreads();
  }

  if (wsel < 2) {
    ushort_t* C = (wsel == 0) ? Qh : Kh;
#pragma unroll
    for (int mi = 0; mi < 4; ++mi)
#pragma unroll
      for (int ni = 0; ni < 4; ++ni) {
        const int col = n0 + wc * 64 + ni * 16 + lr;
        const float bcol = bias[col];
        const int rbase = m0 + wr * 64 + mi * 16 + kg * 4;
#pragma unroll
        for (int r = 0; r < 4; ++r)
          C[(size_t)(rbase + r) * DD + col] = f2bf(acc[mi][ni][r] + bcol);
      }
  } else {
    const int b2 = m0 >> 11;
    const int t0q = m0 & 2047;
#pragma unroll
    for (int mi = 0; mi < 4; ++mi)
#pragma unroll
      for (int ni = 0; ni < 4; ++ni) {
        const int col = n0 + wc * 64 + ni * 16 + lr;
        const float bcol = bias[col];
        const int t32 = (t0q >> 5) + wr * 2 + (mi >> 1);
        const int jloc = kg * 8 + (mi & 1) * 4;
        uint2 pk;
        pk.x = pack2(acc[mi][ni][0] + bcol, acc[mi][ni][1] + bcol);
        pk.y = pack2(acc[mi][ni][2] + bcol, acc[mi][ni][3] + bcol);
        *(uint2*)(VTt + ((size_t)(b2 * 64 + t32)) * (DD * 32) + col * 32 + jloc) = pk;
      }
  }
}

// ---------- split-K flash: grid 1280 = 256 chunks x 5 seg slots ----------
// slot r (bx&255): hb = r&1, b = (r>>1)&3, tc = 31-(r>>3). seg = bx>>8.
// Block = 2 waves x 16 q-rows over <=8 k-tiles; multi-seg chunks merge via
// last-block atomic election. LDS: K dbuf 2x16KB | V dbuf 2x16KB | red.
__global__ __launch_bounds__(128, 1) void k_flash(const ushort_t* __restrict__ Qh,
                                                  const ushort_t* __restrict__ Kh,
                                                  const ushort_t* __restrict__ VTt,
                                                  float* __restrict__ Cur,
                                                  ushort_t* __restrict__ Xh,
                                                  float* __restrict__ out,
                                                  const float* __restrict__ nw,
                                                  const float* __restrict__ nb,
                                                  float* __restrict__ PartO,
                                                  float* __restrict__ PartML,
                                                  int* __restrict__ cnt,
                                                  int lastLayer, int h) {
  __shared__ char lds[66048];   // K dbuf 2x16KB | V dbuf 2x16KB @32768 | red @65536
  __shared__ int s_old;
  const int tid = threadIdx.x;
  const int bx = blockIdx.x;
  const int r = bx & 255;
  const int seg = bx >> 8;
  const int hb = r & 1;
  const int b = (r >> 1) & 3;
  const int tc = 31 - (r >> 3);
  const int nt = tc + 1 + hb;
  const int nseg = (nt + SEGL - 1) / SEGL;
  if (seg >= nseg) return;
  const int kt0 = seg * SEGL;
  const int klen = (nt - kt0 < SEGL) ? (nt - kt0) : SEGL;
  const int t0 = tc * 32;
  const int nc = tc + 1;
  const int dt = 32 + tc;

  const int w = tid >> 6, lane = tid & 63;
  const int kg = lane >> 4, lr = lane & 15;
  const int tloc = w * 16 + lr;
  const int t = t0 + tloc;
  const int r0 = (hb ? T_ : 0) + t;
  const size_t bT2 = (size_t)b * T2;

  short8 qf[8];
  {
    const ushort_t* qb = Qh + (bT2 + r0) * DD + kg * 8;
#pragma unroll
    for (int kk = 0; kk < 8; ++kk) qf[kk] = *(const short8*)(qb + kk * 32);
  }

  const f32x4 z4 = {0.f, 0.f, 0.f, 0.f};
  f32x4 acc_o[16];
#pragma unroll
  for (int db = 0; db < 16; ++db) acc_o[db] = z4;
  float m_run = -1e30f, l_run = 0.f;

#define STAGE(BUF, TILE)                                                                  \
  {                                                                                       \
    const int _t = (TILE);                                                                \
    const char* Vt = (const char*)VTt + ((size_t)(b * 64 + _t)) * 16384;                  \
    _Pragma("unroll") for (int s = 0; s < 8; ++s) {                                       \
      const int row2 = (w * 8 + s) * 2 + (lane >> 5);                                     \
      const int cc2 = lane & 31;                                                          \
      async_copy16((const char*)Kh + ((bT2 + _t * 32 + row2) * DD) * 2 +                  \
                       ((cc2 * 16) ^ ((row2 & 7) << 4)),                                  \
                   lds + (BUF) * 16384 + (w * 8 + s) * 1024);                             \
      async_copy16(Vt + (w * 8 + s) * 1024 + (lane << 4),                                 \
                   lds + 32768 + (BUF) * 16384 + (w * 8 + s) * 1024);                     \
    }                                                                                     \
  }
#define TILEOF(KT) (((KT) < nc) ? (KT) : dt)

  STAGE(0, TILEOF(kt0));

  union U8 { uint4 u; short8 s; };

  for (int ktl = 0; ktl < klen; ++ktl) {
    const int kt = kt0 + ktl;
    const int tile = TILEOF(kt);
    const bool isDiag = (kt >= nc);

    if (ktl + 1 < klen) {
      STAGE((ktl + 1) & 1, TILEOF(kt + 1));
      asm volatile("s_waitcnt vmcnt(16)" ::: "memory");
    } else {
      asm volatile("s_waitcnt vmcnt(0)" ::: "memory");
    }
    __builtin_amdgcn_s_barrier();
    asm volatile("" ::: "memory");

    const char* KsC = lds + (ktl & 1) * 16384;
    const char* VsC = lds + 32768 + (ktl & 1) * 16384;

    // QK^T (swapped): S^T[j = tile*32 + jb*16 + kg*4 + r][q = lr]
    f32x4 sa[2];
#pragma unroll
    for (int jb = 0; jb < 2; ++jb) {
      sa[jb] = z4;
      const int rowj = jb * 16 + lr;
      const int base = rowj * 512;
      const int swj = (rowj & 7) << 4;
#pragma unroll
      for (int kk = 0; kk < 8; ++kk) {
        short8 kf = *(const short8*)(KsC + base + ((kk * 64 + kg * 16) ^ swj));
        sa[jb] = __builtin_amdgcn_mfma_f32_16x16x32_bf16(kf, qf[kk], sa[jb], 0, 0, 0);
      }
    }

    // mask + scale + online softmax with defer-max
    float sv[8];
    float tmax = -1e30f;
#pragma unroll
    for (int jb = 0; jb < 2; ++jb)
#pragma unroll
      for (int rr = 0; rr < 4; ++rr) {
        const int jl = jb * 16 + kg * 4 + rr;
        const bool valid = isDiag ? (jl == tloc) : ((tile * 32 + jl) < t);
        const float x = valid ? sa[jb][rr] * 0.0625f : -1e30f;
        sv[jb * 4 + rr] = x;
        tmax = fmaxf(tmax, x);
      }
    tmax = fmaxf(tmax, __shfl_xor(tmax, 16, 64));
    tmax = fmaxf(tmax, __shfl_xor(tmax, 32, 64));
    if (tmax > m_run + 8.0f) {
      const float fac = __expf(m_run - tmax);
      m_run = tmax;
      l_run *= fac;
#pragma unroll
      for (int db = 0; db < 16; ++db) acc_o[db] *= fac;
    }
    float p[8];
    float psum = 0.f;
#pragma unroll
    for (int e = 0; e < 8; ++e) {
      const float pe = (sv[e] > -1e29f) ? __expf(sv[e] - m_run) : 0.0f;
      p[e] = pe;
      psum += pe;
    }
    psum += __shfl_xor(psum, 16, 64);
    psum += __shfl_xor(psum, 32, 64);
    l_run += psum;

    U8 pf;
    pf.u.x = cvtpk(p[0], p[1]);
    pf.u.y = cvtpk(p[2], p[3]);
    pf.u.z = cvtpk(p[4], p[5]);
    pf.u.w = cvtpk(p[6], p[7]);

    // PV: O^T += V^T * P^T (K=32), V from LDS pi32 layout
#pragma unroll
    for (int db = 0; db < 16; ++db) {
      U8 vf;
      vf.u = *(const uint4*)(VsC + (db * 16 + lr) * 64 + kg * 16);
      acc_o[db] = __builtin_amdgcn_mfma_f32_16x16x32_bf16(vf.s, pf.s, acc_o[db], 0, 0, 0);
    }

    __builtin_amdgcn_s_barrier();
    asm volatile("" ::: "memory");
  }
#undef STAGE

  // ---------- partial write + last-block merge (multi-segment chunks) ----------
  if (nseg > 1) {
    {
      float* pml = PartML + (r * 5 + seg) * 64;
      if (kg == 0) { pml[tloc] = m_run; pml[32 + tloc] = l_run; }
      float* po = PartO + ((size_t)(r * 5 + seg)) * (32 * 256) + tloc * 256 + kg * 4;
#pragma unroll
      for (int db = 0; db < 16; ++db) *(f32x4*)(po + db * 16) = acc_o[db];
    }
    __threadfence();
    __syncthreads();
    if (tid == 0) s_old = atomicAdd(&cnt[r], 1);
    __syncthreads();
    if ((s_old % nseg) != nseg - 1) return;
    __threadfence();
    // merge all segments (fixed order -> deterministic)
    float mstar = -1e30f;
    for (int s = 0; s < nseg; ++s)
      mstar = fmaxf(mstar, PartML[(r * 5 + s) * 64 + tloc]);
    l_run = 0.f;
#pragma unroll
    for (int db = 0; db < 16; ++db) acc_o[db] = z4;
    for (int s = 0; s < nseg; ++s) {
      const float* pml = PartML + (r * 5 + s) * 64;
      const float f = __expf(pml[tloc] - mstar);
      l_run += f * pml[32 + tloc];
      const float* po = PartO + ((size_t)(r * 5 + s)) * (32 * 256) + tloc * 256 + kg * 4;
#pragma unroll
      for (int db = 0; db < 16; ++db) {
        f32x4 v = *(const f32x4*)(po + db * 16);
#pragma unroll
        for (int q = 0; q < 4; ++q) acc_o[db][q] += f * v[q];
      }
    }
  }

  // ---------- epilogue (wave-local; each wave owns its 16 rows) ----------
  const float oinv = 1.0f / l_run;   // t==0 (top): l==0 -> store skipped

  if (!hb) {
    if (t != 0) {
      ushort_t* xp = Xh + (bT2 + t) * DIN + kg * 4;
#pragma unroll
      for (int db = 0; db < 16; ++db) {
        us4v o;
#pragma unroll
        for (int rr = 0; rr < 4; ++rr) o[rr] = f2bf(acc_o[db][rr] * oinv);
        *(us4v*)(xp + db * 16) = o;
      }
    }
  } else {
    float* cp = Cur + ((size_t)b * T_ + t) * DD + kg * 4;
    float s1 = 0.f, s2 = 0.f;
#pragma unroll
    for (int db = 0; db < 16; ++db) {
      f32x4 c4 = *(const f32x4*)(cp + db * 16);
#pragma unroll
      for (int rr = 0; rr < 4; ++rr) {
        const float x = tanhf(acc_o[db][rr] * oinv) + c4[rr];
        acc_o[db][rr] = x;
        s1 += x;
        s2 += x * x;
      }
    }
    s1 += __shfl_xor(s1, 16, 64); s1 += __shfl_xor(s1, 32, 64);
    s2 += __shfl_xor(s2, 16, 64); s2 += __shfl_xor(s2, 32, 64);
    const float mean = s1 * (1.0f / 256.0f);
    const float var = s2 * (1.0f / 256.0f) - mean * mean;
    const float rinv = rsqrtf(var + LNEPS);
    ushort_t* xp = Xh + (bT2 + T_ + t) * DIN + kg * 4;
    if (lastLayer) {
      float* op = out + ((size_t)b * T_ + t) * (DD * 4) + h * DD + kg * 4;
      const us4v zz = {0, 0, 0, 0};
      const f32x4 zf = {0.f, 0.f, 0.f, 0.f};
#pragma unroll
      for (int db = 0; db < 16; ++db) {
        f32x4 w4 = *(const f32x4*)&nw[db * 16 + kg * 4];
        f32x4 b4 = *(const f32x4*)&nb[db * 16 + kg * 4];
        f32x4 y;
#pragma unroll
        for (int rr = 0; rr < 4; ++rr) y[rr] = (acc_o[db][rr] - mean) * rinv * w4[rr] + b4[rr];
        *(f32x4*)(op + db * 16) = y;
        *(f32x4*)(cp + db * 16) = zf;
        *(us4v*)(xp + db * 16) = zz;
      }
    } else {
#pragma unroll
      for (int db = 0; db < 16; ++db) {
        f32x4 w4 = *(const f32x4*)&nw[db * 16 + kg * 4];
        f32x4 b4 = *(const f32x4*)&nb[db * 16 + kg * 4];
        f32x4 y;
        us4v yh;
#pragma unroll
        for (int rr = 0; rr < 4; ++rr) {
          y[rr] = (acc_o[db][rr] - mean) * rinv * w4[rr] + b4[rr];
          yh[rr] = f2bf(y[rr]);
        }
        *(f32x4*)(cp + db * 16) = y;
        *(us4v*)(xp + db * 16) = yh;
      }
    }
  }

  // ---------- row0 mean-V fold (4 lightest top chunks; single-segment) ----------
  if (!hb && tc < 4) {
    float* red = (float*)(lds + 65536);
    const int col = tc * 64 + (tid & 63);
    const int half = tid >> 6;
    float s = 0.f;
    for (int tl = half * 32; tl < half * 32 + 32; ++tl) {
      const ushort_t* vp = VTt + ((size_t)(b * 64 + tl)) * 8192 + col * 32;
#pragma unroll
      for (int j = 0; j < 32; j += 8) {
        uint4 v = *(const uint4*)(vp + j);
        const uint_t vs[4] = {v.x, v.y, v.z, v.w};
#pragma unroll
        for (int q = 0; q < 4; ++q) {
          s += __uint_as_float(vs[q] << 16);
          s += __uint_as_float(vs[q] & 0xffff0000u);
        }
      }
    }
    red[half * 64 + (tid & 63)] = s;
    __syncthreads();
    if (tid < 64)
      Xh[bT2 * DIN + tc * 64 + tid] =
          f2bf((red[tid] + red[64 + tid]) * (1.0f / 2048.0f));
  }
}

extern "C" void kernel_launch(void* const* d_in, const int* in_sizes, int n_in,
                              void* d_out, int out_size, void* d_ws, size_t ws_size,
                              hipStream_t stream) {
  const float* ev = (const float*)d_in[0];
  const float* tm = (const float*)d_in[1];
  const float* Wt = (const float*)d_in[3];
  const float* bt = (const float*)d_in[4];
  const float* Wq = (const float*)d_in[5];
  const float* bq = (const float*)d_in[6];
  const float* Wk = (const float*)d_in[7];
  const float* bk = (const float*)d_in[8];
  const float* Wv = (const float*)d_in[9];
  const float* bv = (const float*)d_in[10];
  const float* nw = (const float*)d_in[11];
  const float* nb = (const float*)d_in[12];
  float* out = (float*)d_out;

  char* p = (char*)d_ws;
  ushort_t* Xh  = (ushort_t*)p; p += (size_t)BB * T2 * DIN * 2;   // 8.39 MB
  ushort_t* Qh  = (ushort_t*)p; p += (size_t)BB * T2 * DD * 2;    // 4.19 MB
  ushort_t* Kh  = (ushort_t*)p; p += (size_t)BB * T2 * DD * 2;
  ushort_t* VTt = (ushort_t*)p; p += (size_t)BB * T2 * DD * 2;    // pi32-tiled V
  float* Cur    = (float*)p;    p += (size_t)BB * T_ * DD * 4;    // 4.19 MB
  ushort_t* WT  = (ushort_t*)p; p += (size_t)36 * DD * DIN * 2;   // 9.44 MB
  float* PartO  = (float*)p;    p += (size_t)256 * 5 * 32 * 256 * 4;  // 41.9 MB
  float* PartML = (float*)p;    p += (size_t)256 * 5 * 64 * 4;        // 0.33 MB
  int* cnt      = (int*)p;                                            // 1 KB

  k_zero<<<1, 256, 0, stream>>>(cnt);
  k_init<<<BB * T_, 256, 0, stream>>>(ev, tm, Wt, bt, Xh, Cur);
  k_transW<<<dim3(36, 32), 256, 0, stream>>>(Wq, Wk, Wv, WT);

  for (int h = 0; h < 4; ++h) {
    for (int l = 0; l < 3; ++l) {
      const int hl = h * 3 + l;
      const size_t boff = (size_t)hl * DD;
      k_qkv<<<dim3(64, 2, 3), 256, 0, stream>>>(Xh, WT, bq + boff, bk + boff, bv + boff,
                                                Qh, Kh, VTt, hl);
      k_flash<<<1280, 128, 0, stream>>>(Qh, Kh, VTt, Cur, Xh, out, nw, nb,
                                        PartO, PartML, cnt, (l == 2) ? 1 : 0, h);
    }
  }
}

// Round 14
// 1143.798 us; speedup vs baseline: 1.1309x; 1.1309x over previous
//
#include <hip/hip_runtime.h>

typedef __attribute__((ext_vector_type(8))) short short8;
typedef __attribute__((ext_vector_type(4))) float f32x4;
typedef __attribute__((ext_vector_type(4))) unsigned short us4v;
typedef unsigned short ushort_t;
typedef unsigned int uint_t;

#define BB 4
#define T_ 1024
#define T2 2048
#define DD 256
#define DIN 512
#define NMARK 64
#define LNEPS 1e-5f
#define KDIV (-0.035977892078032f)

__device__ __forceinline__ ushort_t f2bf(float f) {
  unsigned int u = __float_as_uint(f);
  unsigned int r = (u + 0x7fffu + ((u >> 16) & 1u)) >> 16;
  return (ushort_t)r;
}
__device__ __forceinline__ uint_t pack2(float a, float b) {
  return (uint_t)f2bf(a) | ((uint_t)f2bf(b) << 16);
}
__device__ __forceinline__ uint_t cvtpk(float lo, float hi) {
  uint_t r;
  asm("v_cvt_pk_bf16_f32 %0, %1, %2" : "=v"(r) : "v"(lo), "v"(hi));
  return r;
}

typedef const __attribute__((address_space(1))) unsigned int* as1cu32;
typedef __attribute__((address_space(3))) unsigned int* as3u32;
// sc0 (aux=1): bypass L1 so cross-block repeated-address reads see the XCD L2.
__device__ __forceinline__ void acp16(const void* g, void* l) {
  __builtin_amdgcn_global_load_lds((as1cu32)g, (as3u32)l, 16, 0, 1);
}

// ---------- zero barrier counters ----------
__global__ __launch_bounds__(256) void k_zero(int* __restrict__ cnt) {
  cnt[threadIdx.x] = 0;
}

// ---------- init: type/time embeddings -> Xh (bf16), Cur = 0 ----------
__global__ __launch_bounds__(256) void k_init(const float* __restrict__ ev,
                                              const float* __restrict__ tm,
                                              const float* __restrict__ Wt,
                                              const float* __restrict__ bt,
                                              ushort_t* __restrict__ Xh,
                                              float* __restrict__ Cur) {
  const int btq = blockIdx.x;
  const int b = btq >> 10;
  const int t = btq & 1023;
  const int d = threadIdx.x;
  __shared__ float evs[NMARK];
  if (d < NMARK) evs[d] = ev[(size_t)btq * NMARK + d];
  __syncthreads();
  float s = bt[d];
#pragma unroll
  for (int m = 0; m < NMARK; ++m) s += evs[m] * Wt[m * DD + d];
  const float te_type = tanhf(s);
  const float tv = tm[btq];
  const int i = d >> 1;
  const float dv = expf((float)(2 * i) * KDIV);
  const float ang = tv * dv;
  const float te_time = (d & 1) ? cosf(ang) : sinf(ang);
  ushort_t* Xb = Xh + (size_t)b * T2 * DIN;
  const ushort_t tt = f2bf(te_time);
  Xb[(size_t)t * DIN + d] = f2bf(te_type);
  Xb[(size_t)t * DIN + DD + d] = tt;
  Xb[(size_t)(T_ + t) * DIN + d] = 0;
  Xb[(size_t)(T_ + t) * DIN + DD + d] = tt;
  Cur[((size_t)b * T_ + t) * DD + d] = 0.0f;
}

// ---------- weight transpose: W[hl][k][n] f32 -> WT[mat][n][k] bf16 ----------
__global__ __launch_bounds__(256) void k_transW(const float* __restrict__ Wq,
                                                const float* __restrict__ Wk,
                                                const float* __restrict__ Wv,
                                                ushort_t* __restrict__ WT) {
  const int mi = blockIdx.x;
  const int wsel = mi / 12, hl = mi % 12;
  const float* W = ((wsel == 0) ? Wq : (wsel == 1) ? Wk : Wv) + (size_t)hl * DIN * DD;
  const int t = blockIdx.y;
  const int k0 = (t >> 2) * 64, n0 = (t & 3) * 64;
  __shared__ float Ts[64][65];
  const int tid = threadIdx.x;
#pragma unroll
  for (int i = 0; i < 16; ++i) {
    const int idx = tid + i * 256;
    const int r = idx >> 6, c = idx & 63;
    Ts[r][c] = W[(size_t)(k0 + r) * DD + n0 + c];
  }
  __syncthreads();
  ushort_t* D = WT + (size_t)mi * DD * DIN;
#pragma unroll
  for (int i = 0; i < 16; ++i) {
    const int idx = tid + i * 256;
    const int rn = idx >> 6, ck = idx & 63;
    D[(size_t)(n0 + rn) * DIN + k0 + ck] = f2bf(Ts[ck][rn]);
  }
}

// ---------- persistent mega kernel: 12 iterations of qkv+flash, XCD-local ----------
// bx&7 = XCD (round-robin dispatch assumption); XCD<4 -> batch, else exit.
// s = bx>>3: block owns rows [32s,32s+32) of BOTH halves. LDS 83KB -> 1 block/CU.
__global__ __launch_bounds__(256, 1) void k_mega(ushort_t* __restrict__ Xh,
                                                 ushort_t* __restrict__ Qh,
                                                 ushort_t* __restrict__ Kh,
                                                 ushort_t* __restrict__ VTt,
                                                 float* __restrict__ Cur,
                                                 float* __restrict__ out,
                                                 const ushort_t* __restrict__ WT,
                                                 const float* __restrict__ bq,
                                                 const float* __restrict__ bk,
                                                 const float* __restrict__ bv,
                                                 const float* __restrict__ nw,
                                                 const float* __restrict__ nb,
                                                 int* __restrict__ cnt) {
  __shared__ char lds[84992];
  const int bx = blockIdx.x;
  const int xcd = bx & 7;
  if (xcd >= 4) return;
  const int b = xcd;
  const int s = bx >> 3;              // 0..31
  const int tid = threadIdx.x;
  const int w = tid >> 6, lane = tid & 63;
  const int kg = lane >> 4, lr = lane & 15;
  const size_t bT2 = (size_t)b * T2;
  int* mycnt = cnt + b * 64;
  const f32x4 z4 = {0.f, 0.f, 0.f, 0.f};
  union U8 { uint4 u; short8 sh; };

  for (int hl = 0; hl < 12; ++hl) {
    const int h = hl / 3;
    const int lastLayer = ((hl % 3) == 2) ? 1 : 0;

    // ================= qkv phase =================
    // stage X rows (own 64 rows: top32 + bottom32), swizzled, sc0
#pragma unroll
    for (int i = 0; i < 16; ++i) {
      const int idx = tid + i * 256;
      const int rr = idx >> 6, ch = idx & 63;
      const int g = (rr < 32) ? (s * 32 + rr) : (T_ + s * 32 + rr - 32);
      acp16((const char*)Xh + (bT2 + g) * 1024 + ((ch * 16) ^ ((rr & 7) << 4)),
            lds + idx * 16);
    }
    __syncthreads();

    for (int mt = 0; mt < 3; ++mt) {
      const ushort_t* Wb = WT + ((size_t)(mt * 12 + hl)) * (DD * DIN) + (size_t)(w * 64) * DIN;
      const float* bias = ((mt == 0) ? bq : (mt == 1) ? bk : bv) + hl * DD + w * 64;
      f32x4 acc[4][4];
#pragma unroll
      for (int a = 0; a < 4; ++a)
#pragma unroll
        for (int c = 0; c < 4; ++c) acc[a][c] = z4;

      for (int ks = 0; ks < 16; ++ks) {
        const int cb = ks * 64 + kg * 16;
        short8 af[4], bf[4];
#pragma unroll
        for (int mi = 0; mi < 4; ++mi) {
          const int row = mi * 16 + lr;
          af[mi] = *(const short8*)(lds + row * 1024 + (cb ^ ((row & 7) << 4)));
        }
#pragma unroll
        for (int ni = 0; ni < 4; ++ni) {
          const int cl = ni * 16 + lr;
          bf[ni] = *(const short8*)(Wb + (size_t)cl * DIN + ks * 32 + kg * 8);
        }
#pragma unroll
        for (int mi = 0; mi < 4; ++mi)
#pragma unroll
          for (int ni = 0; ni < 4; ++ni)
            acc[mi][ni] = __builtin_amdgcn_mfma_f32_16x16x32_bf16(af[mi], bf[ni], acc[mi][ni], 0, 0, 0);
      }
#pragma unroll
      for (int mi = 0; mi < 4; ++mi)
#pragma unroll
        for (int ni = 0; ni < 4; ++ni) {
          const int col = w * 64 + ni * 16 + lr;
          const float bc = bias[ni * 16 + lr];
          if (mt < 2) {
            ushort_t* C = (mt == 0) ? Qh : Kh;
#pragma unroll
            for (int r = 0; r < 4; ++r) {
              const int local = mi * 16 + kg * 4 + r;
              const int g = (local < 32) ? (s * 32 + local) : (T_ + s * 32 + local - 32);
              C[(bT2 + g) * DD + col] = f2bf(acc[mi][ni][r] + bc);
            }
          } else {
            const int tile = (mi < 2) ? s : (32 + s);
            const int jloc = kg * 8 + (mi & 1) * 4;
            uint2 pk;
            pk.x = pack2(acc[mi][ni][0] + bc, acc[mi][ni][1] + bc);
            pk.y = pack2(acc[mi][ni][2] + bc, acc[mi][ni][3] + bc);
            *(uint2*)(VTt + ((size_t)(b * 64 + tile)) * 8192 + col * 32 + jloc) = pk;
          }
        }
    }

    // ---- XCD-local barrier #1 (qkv done) ----
    __syncthreads();           // drains vmcnt/lgkmcnt per wave
    if (tid == 0) {
      __hip_atomic_fetch_add(&mycnt[hl * 2], 1, __ATOMIC_RELAXED, __HIP_MEMORY_SCOPE_AGENT);
      while (__hip_atomic_load(&mycnt[hl * 2], __ATOMIC_RELAXED, __HIP_MEMORY_SCOPE_AGENT) < 32)
        __builtin_amdgcn_s_sleep(8);
    }
    __syncthreads();

    // ================= flash phase =================
    const int half = w >> 1;              // 0 = top, 1 = bottom
    const int tloc = (w & 1) * 16 + lr;
    const int t = s * 32 + tloc;
    const int r0 = (half ? T_ : 0) + t;
    const int ntop = s + 1;
    const int nt = s + 2;                 // +diag (bottom only computes it)
    const int dt = 32 + s;

    short8 qf[8];
    {
      const ushort_t* qb = Qh + (bT2 + r0) * DD + kg * 8;
#pragma unroll
      for (int kk = 0; kk < 8; ++kk) qf[kk] = *(const short8*)(qb + kk * 32);
    }
    f32x4 acc_o[16];
#pragma unroll
    for (int db = 0; db < 16; ++db) acc_o[db] = z4;
    float m_run = -1e30f, l_run = 0.f;

#define STAGE(BUF, TILE)                                                                  \
    {                                                                                     \
      const int _t = (TILE);                                                              \
      const char* Vt = (const char*)VTt + ((size_t)(b * 64 + _t)) * 16384;                \
      _Pragma("unroll") for (int sj = 0; sj < 4; ++sj) {                                  \
        const int c = w * 4 + sj;                                                         \
        const int row2 = (c << 1) | (lane >> 5);                                          \
        const int cc2 = lane & 31;                                                        \
        acp16((const char*)Kh + ((bT2 + _t * 32 + row2) * DD) * 2 +                       \
                  ((cc2 * 16) ^ ((row2 & 7) << 4)),                                       \
              lds + (BUF) * 16384 + c * 1024);                                            \
        acp16(Vt + c * 1024 + lane * 16,                                                  \
              lds + 32768 + (BUF) * 16384 + c * 1024);                                    \
      }                                                                                   \
    }

    STAGE(0, 0);
    for (int kt = 0; kt < nt; ++kt) {
      const bool isDiag = (kt >= ntop);
      const int tile = isDiag ? dt : kt;
      if (kt + 1 < nt) {
        STAGE((kt + 1) & 1, (kt + 1 >= ntop) ? dt : (kt + 1));
        asm volatile("s_waitcnt vmcnt(8)" ::: "memory");
      } else {
        asm volatile("s_waitcnt vmcnt(0)" ::: "memory");
      }
      __builtin_amdgcn_s_barrier();
      asm volatile("" ::: "memory");

      if (!isDiag || half) {
        const char* KsC = lds + (kt & 1) * 16384;
        const char* VsC = lds + 32768 + (kt & 1) * 16384;
        f32x4 sa[2];
#pragma unroll
        for (int jb = 0; jb < 2; ++jb) {
          sa[jb] = z4;
          const int rowj = jb * 16 + lr;
          const int base = rowj * 512;
          const int swj = (rowj & 7) << 4;
#pragma unroll
          for (int kk = 0; kk < 8; ++kk) {
            short8 kf = *(const short8*)(KsC + base + ((kk * 64 + kg * 16) ^ swj));
            sa[jb] = __builtin_amdgcn_mfma_f32_16x16x32_bf16(kf, qf[kk], sa[jb], 0, 0, 0);
          }
        }
        float sv[8];
        float tmax = -1e30f;
#pragma unroll
        for (int jb = 0; jb < 2; ++jb)
#pragma unroll
          for (int rr = 0; rr < 4; ++rr) {
            const int jl = jb * 16 + kg * 4 + rr;
            const bool valid = isDiag ? (jl == tloc) : ((tile * 32 + jl) < t);
            const float x = valid ? sa[jb][rr] * 0.0625f : -1e30f;
            sv[jb * 4 + rr] = x;
            tmax = fmaxf(tmax, x);
          }
        tmax = fmaxf(tmax, __shfl_xor(tmax, 16, 64));
        tmax = fmaxf(tmax, __shfl_xor(tmax, 32, 64));
        if (tmax > m_run + 8.0f) {
          const float fac = __expf(m_run - tmax);
          m_run = tmax;
          l_run *= fac;
#pragma unroll
          for (int db = 0; db < 16; ++db) acc_o[db] *= fac;
        }
        float p[8];
        float psum = 0.f;
#pragma unroll
        for (int e = 0; e < 8; ++e) {
          const float pe = (sv[e] > -1e29f) ? __expf(sv[e] - m_run) : 0.0f;
          p[e] = pe;
          psum += pe;
        }
        psum += __shfl_xor(psum, 16, 64);
        psum += __shfl_xor(psum, 32, 64);
        l_run += psum;

        U8 pf;
        pf.u.x = cvtpk(p[0], p[1]);
        pf.u.y = cvtpk(p[2], p[3]);
        pf.u.z = cvtpk(p[4], p[5]);
        pf.u.w = cvtpk(p[6], p[7]);
#pragma unroll
        for (int db = 0; db < 16; ++db) {
          U8 vf;
          vf.u = *(const uint4*)(VsC + (db * 16 + lr) * 64 + kg * 16);
          acc_o[db] = __builtin_amdgcn_mfma_f32_16x16x32_bf16(vf.sh, pf.sh, acc_o[db], 0, 0, 0);
        }
      }
      __builtin_amdgcn_s_barrier();
      asm volatile("" ::: "memory");
    }
#undef STAGE

    // ---- epilogue ----
    const float oinv = 1.0f / l_run;
    if (!half) {
      if (t != 0) {
        ushort_t* xp = Xh + (bT2 + t) * DIN + kg * 4;
#pragma unroll
        for (int db = 0; db < 16; ++db) {
          us4v o;
#pragma unroll
          for (int rr = 0; rr < 4; ++rr) o[rr] = f2bf(acc_o[db][rr] * oinv);
          *(us4v*)(xp + db * 16) = o;
        }
      }
    } else {
      float* cp = Cur + ((size_t)b * T_ + t) * DD + kg * 4;
      float s1 = 0.f, s2 = 0.f;
#pragma unroll
      for (int db = 0; db < 16; ++db) {
        f32x4 c4 = *(const f32x4*)(cp + db * 16);
#pragma unroll
        for (int rr = 0; rr < 4; ++rr) {
          const float x = tanhf(acc_o[db][rr] * oinv) + c4[rr];
          acc_o[db][rr] = x;
          s1 += x;
          s2 += x * x;
        }
      }
      s1 += __shfl_xor(s1, 16, 64); s1 += __shfl_xor(s1, 32, 64);
      s2 += __shfl_xor(s2, 16, 64); s2 += __shfl_xor(s2, 32, 64);
      const float mean = s1 * (1.0f / 256.0f);
      const float var = s2 * (1.0f / 256.0f) - mean * mean;
      const float rinv = rsqrtf(var + LNEPS);
      ushort_t* xp = Xh + (bT2 + T_ + t) * DIN + kg * 4;
      if (lastLayer) {
        float* op = out + ((size_t)b * T_ + t) * (DD * 4) + h * DD + kg * 4;
        const us4v zz = {0, 0, 0, 0};
        const f32x4 zf = {0.f, 0.f, 0.f, 0.f};
#pragma unroll
        for (int db = 0; db < 16; ++db) {
          f32x4 w4 = *(const f32x4*)&nw[db * 16 + kg * 4];
          f32x4 b4 = *(const f32x4*)&nb[db * 16 + kg * 4];
          f32x4 y;
#pragma unroll
          for (int rr = 0; rr < 4; ++rr) y[rr] = (acc_o[db][rr] - mean) * rinv * w4[rr] + b4[rr];
          *(f32x4*)(op + db * 16) = y;
          *(f32x4*)(cp + db * 16) = zf;
          *(us4v*)(xp + db * 16) = zz;
        }
      } else {
#pragma unroll
        for (int db = 0; db < 16; ++db) {
          f32x4 w4 = *(const f32x4*)&nw[db * 16 + kg * 4];
          f32x4 b4 = *(const f32x4*)&nb[db * 16 + kg * 4];
          f32x4 y;
          us4v yh;
#pragma unroll
          for (int rr = 0; rr < 4; ++rr) {
            y[rr] = (acc_o[db][rr] - mean) * rinv * w4[rr] + b4[rr];
            yh[rr] = f2bf(y[rr]);
          }
          *(f32x4*)(cp + db * 16) = y;
          *(us4v*)(xp + db * 16) = yh;
        }
      }
    }

    // ---- row0 mean-V fold (blocks s<4, col-slice s*64..) ----
    if (s < 4) {
      __syncthreads();
      float facc = 0.f;
      const int d = tid & 63;
      const int jg = tid >> 6;
      for (int t8 = 0; t8 < 8; ++t8) {
#pragma unroll
        for (int e = 0; e < 2; ++e) {
          const int tl = t8 * 8 + w * 2 + e;
#pragma unroll
          for (int q = 0; q < 4; ++q)
            acp16((const char*)VTt + ((size_t)(b * 64 + tl)) * 16384 + s * 4096 + q * 1024 + lane * 16,
                  lds + (w * 2 + e) * 4096 + q * 1024);
        }
        asm volatile("s_waitcnt vmcnt(0)" ::: "memory");
        __syncthreads();
        for (int tl8 = 0; tl8 < 8; ++tl8) {
          const ushort_t* sl = (const ushort_t*)(lds + tl8 * 4096) + d * 32 + jg * 8;
#pragma unroll
          for (int j = 0; j < 8; ++j)
            facc += __uint_as_float(((uint_t)sl[j]) << 16);
        }
        __syncthreads();
      }
      float* red = (float*)lds;
      red[jg * 64 + d] = facc;
      __syncthreads();
      if (tid < 64) {
        const float tot = red[tid] + red[64 + tid] + red[128 + tid] + red[192 + tid];
        Xh[bT2 * DIN + s * 64 + tid] = f2bf(tot * (1.0f / 2048.0f));
      }
    }

    // ---- XCD-local barrier #2 (flash done) ----
    __syncthreads();
    if (tid == 0) {
      __hip_atomic_fetch_add(&mycnt[hl * 2 + 1], 1, __ATOMIC_RELAXED, __HIP_MEMORY_SCOPE_AGENT);
      while (__hip_atomic_load(&mycnt[hl * 2 + 1], __ATOMIC_RELAXED, __HIP_MEMORY_SCOPE_AGENT) < 32)
        __builtin_amdgcn_s_sleep(8);
    }
    __syncthreads();
  }
}

extern "C" void kernel_launch(void* const* d_in, const int* in_sizes, int n_in,
                              void* d_out, int out_size, void* d_ws, size_t ws_size,
                              hipStream_t stream) {
  const float* ev = (const float*)d_in[0];
  const float* tm = (const float*)d_in[1];
  const float* Wt = (const float*)d_in[3];
  const float* bt = (const float*)d_in[4];
  const float* Wq = (const float*)d_in[5];
  const float* bq = (const float*)d_in[6];
  const float* Wk = (const float*)d_in[7];
  const float* bk = (const float*)d_in[8];
  const float* Wv = (const float*)d_in[9];
  const float* bv = (const float*)d_in[10];
  const float* nw = (const float*)d_in[11];
  const float* nb = (const float*)d_in[12];
  float* out = (float*)d_out;

  char* p = (char*)d_ws;
  ushort_t* Xh  = (ushort_t*)p; p += (size_t)BB * T2 * DIN * 2;   // 8.39 MB
  ushort_t* Qh  = (ushort_t*)p; p += (size_t)BB * T2 * DD * 2;    // 4.19 MB
  ushort_t* Kh  = (ushort_t*)p; p += (size_t)BB * T2 * DD * 2;
  ushort_t* VTt = (ushort_t*)p; p += (size_t)BB * T2 * DD * 2;    // pi32-tiled V
  float* Cur    = (float*)p;    p += (size_t)BB * T_ * DD * 4;    // 4.19 MB
  ushort_t* WT  = (ushort_t*)p; p += (size_t)36 * DD * DIN * 2;   // 9.44 MB
  int* cnt      = (int*)p;                                         // 1 KB

  k_zero<<<1, 256, 0, stream>>>(cnt);
  k_init<<<BB * T_, 256, 0, stream>>>(ev, tm, Wt, bt, Xh, Cur);
  k_transW<<<dim3(36, 32), 256, 0, stream>>>(Wq, Wk, Wv, WT);
  k_mega<<<256, 256, 0, stream>>>(Xh, Qh, Kh, VTt, Cur, out, WT,
                                  bq, bk, bv, nw, nb, cnt);
}

// Round 15
// 783.797 us; speedup vs baseline: 1.6503x; 1.4593x over previous
//
#include <hip/hip_runtime.h>

typedef __attribute__((ext_vector_type(8))) short short8;
typedef __attribute__((ext_vector_type(4))) float f32x4;
typedef __attribute__((ext_vector_type(4))) unsigned short us4v;
typedef unsigned short ushort_t;
typedef unsigned int uint_t;

#define BB 4
#define T_ 1024
#define T2 2048
#define DD 256
#define DIN 512
#define NMARK 64
#define LNEPS 1e-5f
#define KDIV (-0.035977892078032f)
#define SEGL 8

__device__ __forceinline__ ushort_t f2bf(float f) {
  unsigned int u = __float_as_uint(f);
  unsigned int r = (u + 0x7fffu + ((u >> 16) & 1u)) >> 16;
  return (ushort_t)r;
}
__device__ __forceinline__ uint_t pack2(float a, float b) {
  return (uint_t)f2bf(a) | ((uint_t)f2bf(b) << 16);
}
__device__ __forceinline__ uint_t cvtpk(float lo, float hi) {
  uint_t r;
  asm("v_cvt_pk_bf16_f32 %0, %1, %2" : "=v"(r) : "v"(lo), "v"(hi));
  return r;
}

typedef const __attribute__((address_space(1))) unsigned int* as1cu32;
typedef __attribute__((address_space(3))) unsigned int* as3u32;
__device__ __forceinline__ void async_copy16(const void* g, void* l) {
  __builtin_amdgcn_global_load_lds((as1cu32)g, (as3u32)l, 16, 0, 0);
}

// ---------- init: type/time embeddings -> Xh (bf16), Cur = 0 ----------
__global__ __launch_bounds__(256) void k_init(const float* __restrict__ ev,
                                              const float* __restrict__ tm,
                                              const float* __restrict__ Wt,
                                              const float* __restrict__ bt,
                                              ushort_t* __restrict__ Xh,
                                              float* __restrict__ Cur) {
  const int btq = blockIdx.x;
  const int b = btq >> 10;
  const int t = btq & 1023;
  const int d = threadIdx.x;
  __shared__ float evs[NMARK];
  if (d < NMARK) evs[d] = ev[(size_t)btq * NMARK + d];
  __syncthreads();
  float s = bt[d];
#pragma unroll
  for (int m = 0; m < NMARK; ++m) s += evs[m] * Wt[m * DD + d];
  const float te_type = tanhf(s);
  const float tv = tm[btq];
  const int i = d >> 1;
  const float dv = expf((float)(2 * i) * KDIV);
  const float ang = tv * dv;
  const float te_time = (d & 1) ? cosf(ang) : sinf(ang);
  ushort_t* Xb = Xh + (size_t)b * T2 * DIN;
  const ushort_t tt = f2bf(te_time);
  Xb[(size_t)t * DIN + d] = f2bf(te_type);
  Xb[(size_t)t * DIN + DD + d] = tt;
  Xb[(size_t)(T_ + t) * DIN + d] = 0;
  Xb[(size_t)(T_ + t) * DIN + DD + d] = tt;
  Cur[((size_t)b * T_ + t) * DD + d] = 0.0f;
}

// ---------- weight transpose: W[hl][k][n] f32 -> WT[mat][n][k] bf16 ----------
__global__ __launch_bounds__(256) void k_transW(const float* __restrict__ Wq,
                                                const float* __restrict__ Wk,
                                                const float* __restrict__ Wv,
                                                ushort_t* __restrict__ WT) {
  const int mi = blockIdx.x;
  const int wsel = mi / 12, hl = mi % 12;
  const float* W = ((wsel == 0) ? Wq : (wsel == 1) ? Wk : Wv) + (size_t)hl * DIN * DD;
  const int t = blockIdx.y;
  const int k0 = (t >> 2) * 64, n0 = (t & 3) * 64;
  __shared__ float Ts[64][65];
  const int tid = threadIdx.x;
#pragma unroll
  for (int i = 0; i < 16; ++i) {
    const int idx = tid + i * 256;
    const int r = idx >> 6, c = idx & 63;
    Ts[r][c] = W[(size_t)(k0 + r) * DD + n0 + c];
  }
  __syncthreads();
  ushort_t* D = WT + (size_t)mi * DD * DIN;
#pragma unroll
  for (int i = 0; i < 16; ++i) {
    const int idx = tid + i * 256;
    const int rn = idx >> 6, ck = idx & 63;
    D[(size_t)(n0 + rn) * DIN + k0 + ck] = f2bf(Ts[ck][rn]);
  }
}

// ---------- QKV GEMM; V written pi32-permuted into 32-wide TILES ----------
__global__ __launch_bounds__(256) void k_qkv(const ushort_t* __restrict__ Xh,
                                             const ushort_t* __restrict__ WT,
                                             const float* __restrict__ bq,
                                             const float* __restrict__ bk,
                                             const float* __restrict__ bv,
                                             ushort_t* __restrict__ Qh,
                                             ushort_t* __restrict__ Kh,
                                             ushort_t* __restrict__ VTt,
                                             int hl) {
  const int m0 = blockIdx.x * 128;
  const int n0 = blockIdx.y * 128;
  const int wsel = blockIdx.z;
  const ushort_t* Bt = WT + ((size_t)(wsel * 12 + hl)) * DD * DIN + (size_t)n0 * DIN;
  const float* bias = (wsel == 0) ? bq : (wsel == 1) ? bk : bv;

  __shared__ ushort_t As[128 * 64];
  __shared__ ushort_t Bs[128 * 64];
  const int tid = threadIdx.x;
  const int w = tid >> 6, lane = tid & 63;
  const int wr = w >> 1, wc = w & 1;
  const int lr = lane & 15, kg = lane >> 4;

  f32x4 acc[4][4];
  const f32x4 z4 = {0.f, 0.f, 0.f, 0.f};
#pragma unroll
  for (int a = 0; a < 4; ++a)
#pragma unroll
    for (int c = 0; c < 4; ++c) acc[a][c] = z4;

  for (int k0 = 0; k0 < DIN; k0 += 64) {
#pragma unroll
    for (int i = 0; i < 4; ++i) {
      const int idx = tid + i * 256;
      const int row = idx >> 3, ch = idx & 7;
      const int db = row * 128 + ((ch * 16) ^ ((row & 7) << 4));
      uint4 va = *(const uint4*)&Xh[(size_t)(m0 + row) * DIN + k0 + ch * 8];
      *(uint4*)((char*)As + db) = va;
      uint4 vb = *(const uint4*)&Bt[(size_t)row * DIN + k0 + ch * 8];
      *(uint4*)((char*)Bs + db) = vb;
    }
    __syncthreads();
#pragma unroll
    for (int kk = 0; kk < 2; ++kk) {
      short8 af[4], bfr[4];
      const int cb = kk * 64 + kg * 16;
#pragma unroll
      for (int mi = 0; mi < 4; ++mi) {
        const int row = wr * 64 + mi * 16 + lr;
        af[mi] = *(const short8*)((const char*)As + row * 128 + (cb ^ ((row & 7) << 4)));
      }
#pragma unroll
      for (int ni = 0; ni < 4; ++ni) {
        const int row = wc * 64 + ni * 16 + lr;
        bfr[ni] = *(const short8*)((const char*)Bs + row * 128 + (cb ^ ((row & 7) << 4)));
      }
#pragma unroll
      for (int mi = 0; mi < 4; ++mi)
#pragma unroll
        for (int ni = 0; ni < 4; ++ni)
          acc[mi][ni] = __builtin_amdgcn_mfma_f32_16x16x32_bf16(af[mi], bfr[ni], acc[mi][ni], 0, 0, 0);
    }
    __syncthreads();
  }

  if (wsel < 2) {
    ushort_t* C = (wsel == 0) ? Qh : Kh;
#pragma unroll
    for (int mi = 0; mi < 4; ++mi)
#pragma unroll
      for (int ni = 0; ni < 4; ++ni) {
        const int col = n0 + wc * 64 + ni * 16 + lr;
        const float bcol = bias[col];
        const int rbase = m0 + wr * 64 + mi * 16 + kg * 4;
#pragma unroll
        for (int r = 0; r < 4; ++r)
          C[(size_t)(rbase + r) * DD + col] = f2bf(acc[mi][ni][r] + bcol);
      }
  } else {
    const int b2 = m0 >> 11;
    const int t0q = m0 & 2047;
#pragma unroll
    for (int mi = 0; mi < 4; ++mi)
#pragma unroll
      for (int ni = 0; ni < 4; ++ni) {
        const int col = n0 + wc * 64 + ni * 16 + lr;
        const float bcol = bias[col];
        const int t32 = (t0q >> 5) + wr * 2 + (mi >> 1);
        const int jloc = kg * 8 + (mi & 1) * 4;
        uint2 pk;
        pk.x = pack2(acc[mi][ni][0] + bcol, acc[mi][ni][1] + bcol);
        pk.y = pack2(acc[mi][ni][2] + bcol, acc[mi][ni][3] + bcol);
        *(uint2*)(VTt + ((size_t)(b2 * 64 + t32)) * (DD * 32) + col * 32 + jloc) = pk;
      }
  }
}

// ---------- flash partial: grid 1280 = 256 chunks x 5 seg slots ----------
// slot r (bx&255): hb = r&1, b = (r>>1)&3, tc = 31-(r>>3). seg = bx>>8.
// Block = 2 waves x 16 q-rows over <=8 k-tiles; ALWAYS writes (m,l,O^T) partial.
// No atomics/fences; a separate merge kernel combines (kernel boundary = sync).
__global__ __launch_bounds__(128, 1) void k_fpart(const ushort_t* __restrict__ Qh,
                                                  const ushort_t* __restrict__ Kh,
                                                  const ushort_t* __restrict__ VTt,
                                                  float* __restrict__ PartO,
                                                  float* __restrict__ PartML) {
  __shared__ char lds[65536];   // K dbuf 2x16KB | V dbuf 2x16KB @32768
  const int tid = threadIdx.x;
  const int bx = blockIdx.x;
  const int r = bx & 255;
  const int seg = bx >> 8;
  const int hb = r & 1;
  const int b = (r >> 1) & 3;
  const int tc = 31 - (r >> 3);
  const int nt = tc + 1 + hb;
  const int nseg = (nt + SEGL - 1) / SEGL;
  if (seg >= nseg) return;
  const int kt0 = seg * SEGL;
  const int klen = (nt - kt0 < SEGL) ? (nt - kt0) : SEGL;
  const int t0 = tc * 32;
  const int nc = tc + 1;
  const int dt = 32 + tc;

  const int w = tid >> 6, lane = tid & 63;
  const int kg = lane >> 4, lr = lane & 15;
  const int tloc = w * 16 + lr;
  const int t = t0 + tloc;
  const int r0 = (hb ? T_ : 0) + t;
  const size_t bT2 = (size_t)b * T2;

  short8 qf[8];
  {
    const ushort_t* qb = Qh + (bT2 + r0) * DD + kg * 8;
#pragma unroll
    for (int kk = 0; kk < 8; ++kk) qf[kk] = *(const short8*)(qb + kk * 32);
  }

  const f32x4 z4 = {0.f, 0.f, 0.f, 0.f};
  f32x4 acc_o[16];
#pragma unroll
  for (int db = 0; db < 16; ++db) acc_o[db] = z4;
  float m_run = -1e30f, l_run = 0.f;

#define STAGE(BUF, TILE)                                                                  \
  {                                                                                       \
    const int _t = (TILE);                                                                \
    const char* Vt = (const char*)VTt + ((size_t)(b * 64 + _t)) * 16384;                  \
    _Pragma("unroll") for (int s = 0; s < 8; ++s) {                                       \
      const int row2 = (w * 8 + s) * 2 + (lane >> 5);                                     \
      const int cc2 = lane & 31;                                                          \
      async_copy16((const char*)Kh + ((bT2 + _t * 32 + row2) * DD) * 2 +                  \
                       ((cc2 * 16) ^ ((row2 & 7) << 4)),                                  \
                   lds + (BUF) * 16384 + (w * 8 + s) * 1024);                             \
      async_copy16(Vt + (w * 8 + s) * 1024 + (lane << 4),                                 \
                   lds + 32768 + (BUF) * 16384 + (w * 8 + s) * 1024);                     \
    }                                                                                     \
  }
#define TILEOF(KT) (((KT) < nc) ? (KT) : dt)

  STAGE(0, TILEOF(kt0));

  union U8 { uint4 u; short8 s; };

  for (int ktl = 0; ktl < klen; ++ktl) {
    const int kt = kt0 + ktl;
    const int tile = TILEOF(kt);
    const bool isDiag = (kt >= nc);

    if (ktl + 1 < klen) {
      STAGE((ktl + 1) & 1, TILEOF(kt + 1));
      asm volatile("s_waitcnt vmcnt(16)" ::: "memory");
    } else {
      asm volatile("s_waitcnt vmcnt(0)" ::: "memory");
    }
    __builtin_amdgcn_s_barrier();
    asm volatile("" ::: "memory");

    const char* KsC = lds + (ktl & 1) * 16384;
    const char* VsC = lds + 32768 + (ktl & 1) * 16384;

    // QK^T (swapped): S^T[j = tile*32 + jb*16 + kg*4 + r][q = lr]
    f32x4 sa[2];
#pragma unroll
    for (int jb = 0; jb < 2; ++jb) {
      sa[jb] = z4;
      const int rowj = jb * 16 + lr;
      const int base = rowj * 512;
      const int swj = (rowj & 7) << 4;
#pragma unroll
      for (int kk = 0; kk < 8; ++kk) {
        short8 kf = *(const short8*)(KsC + base + ((kk * 64 + kg * 16) ^ swj));
        sa[jb] = __builtin_amdgcn_mfma_f32_16x16x32_bf16(kf, qf[kk], sa[jb], 0, 0, 0);
      }
    }

    // mask + scale + online softmax with defer-max
    float sv[8];
    float tmax = -1e30f;
#pragma unroll
    for (int jb = 0; jb < 2; ++jb)
#pragma unroll
      for (int rr = 0; rr < 4; ++rr) {
        const int jl = jb * 16 + kg * 4 + rr;
        const bool valid = isDiag ? (jl == tloc) : ((tile * 32 + jl) < t);
        const float x = valid ? sa[jb][rr] * 0.0625f : -1e30f;
        sv[jb * 4 + rr] = x;
        tmax = fmaxf(tmax, x);
      }
    tmax = fmaxf(tmax, __shfl_xor(tmax, 16, 64));
    tmax = fmaxf(tmax, __shfl_xor(tmax, 32, 64));
    if (tmax > m_run + 8.0f) {
      const float fac = __expf(m_run - tmax);
      m_run = tmax;
      l_run *= fac;
#pragma unroll
      for (int db = 0; db < 16; ++db) acc_o[db] *= fac;
    }
    float p[8];
    float psum = 0.f;
#pragma unroll
    for (int e = 0; e < 8; ++e) {
      const float pe = (sv[e] > -1e29f) ? __expf(sv[e] - m_run) : 0.0f;
      p[e] = pe;
      psum += pe;
    }
    psum += __shfl_xor(psum, 16, 64);
    psum += __shfl_xor(psum, 32, 64);
    l_run += psum;

    U8 pf;
    pf.u.x = cvtpk(p[0], p[1]);
    pf.u.y = cvtpk(p[2], p[3]);
    pf.u.z = cvtpk(p[4], p[5]);
    pf.u.w = cvtpk(p[6], p[7]);

    // PV: O^T += V^T * P^T (K=32), V from LDS pi32 layout
#pragma unroll
    for (int db = 0; db < 16; ++db) {
      U8 vf;
      vf.u = *(const uint4*)(VsC + (db * 16 + lr) * 64 + kg * 16);
      acc_o[db] = __builtin_amdgcn_mfma_f32_16x16x32_bf16(vf.s, pf.s, acc_o[db], 0, 0, 0);
    }

    __builtin_amdgcn_s_barrier();
    asm volatile("" ::: "memory");
  }
#undef STAGE
#undef TILEOF

  // ---------- write partial ----------
  float* pml = PartML + (r * 5 + seg) * 64;
  if (kg == 0) { pml[tloc] = m_run; pml[32 + tloc] = l_run; }
  float* po = PartO + ((size_t)(r * 5 + seg)) * (32 * 256) + tloc * 256 + kg * 4;
#pragma unroll
  for (int db = 0; db < 16; ++db) *(f32x4*)(po + db * 16) = acc_o[db];
}

// ---------- merge + epilogue: grid 256 (one block per chunk) x 128 ----------
__global__ __launch_bounds__(128) void k_merge(const ushort_t* __restrict__ VTt,
                                               float* __restrict__ Cur,
                                               ushort_t* __restrict__ Xh,
                                               float* __restrict__ out,
                                               const float* __restrict__ nw,
                                               const float* __restrict__ nb,
                                               const float* __restrict__ PartO,
                                               const float* __restrict__ PartML,
                                               int lastLayer, int h) {
  __shared__ float red[128];
  const int tid = threadIdx.x;
  const int r = blockIdx.x;
  const int hb = r & 1;
  const int b = (r >> 1) & 3;
  const int tc = 31 - (r >> 3);
  const int nt = tc + 1 + hb;
  const int nseg = (nt + SEGL - 1) / SEGL;
  const int t0 = tc * 32;

  const int w = tid >> 6, lane = tid & 63;
  const int kg = lane >> 4, lr = lane & 15;
  const int tloc = w * 16 + lr;
  const int t = t0 + tloc;
  const size_t bT2 = (size_t)b * T2;
  const f32x4 z4 = {0.f, 0.f, 0.f, 0.f};

  // merge segments (fixed order -> deterministic)
  float mstar = -1e30f;
  for (int s = 0; s < nseg; ++s)
    mstar = fmaxf(mstar, PartML[(r * 5 + s) * 64 + tloc]);
  float l_run = 0.f;
  f32x4 acc_o[16];
#pragma unroll
  for (int db = 0; db < 16; ++db) acc_o[db] = z4;
  for (int s = 0; s < nseg; ++s) {
    const float* pml = PartML + (r * 5 + s) * 64;
    const float f = __expf(pml[tloc] - mstar);
    l_run += f * pml[32 + tloc];
    const float* po = PartO + ((size_t)(r * 5 + s)) * (32 * 256) + tloc * 256 + kg * 4;
#pragma unroll
    for (int db = 0; db < 16; ++db) {
      f32x4 v = *(const f32x4*)(po + db * 16);
#pragma unroll
      for (int q = 0; q < 4; ++q) acc_o[db][q] += f * v[q];
    }
  }

  const float oinv = 1.0f / l_run;   // t==0 (top): l==0 -> store skipped

  if (!hb) {
    if (t != 0) {
      ushort_t* xp = Xh + (bT2 + t) * DIN + kg * 4;
#pragma unroll
      for (int db = 0; db < 16; ++db) {
        us4v o;
#pragma unroll
        for (int rr = 0; rr < 4; ++rr) o[rr] = f2bf(acc_o[db][rr] * oinv);
        *(us4v*)(xp + db * 16) = o;
      }
    }
  } else {
    float* cp = Cur + ((size_t)b * T_ + t) * DD + kg * 4;
    float s1 = 0.f, s2 = 0.f;
#pragma unroll
    for (int db = 0; db < 16; ++db) {
      f32x4 c4 = *(const f32x4*)(cp + db * 16);
#pragma unroll
      for (int rr = 0; rr < 4; ++rr) {
        const float x = tanhf(acc_o[db][rr] * oinv) + c4[rr];
        acc_o[db][rr] = x;
        s1 += x;
        s2 += x * x;
      }
    }
    s1 += __shfl_xor(s1, 16, 64); s1 += __shfl_xor(s1, 32, 64);
    s2 += __shfl_xor(s2, 16, 64); s2 += __shfl_xor(s2, 32, 64);
    const float mean = s1 * (1.0f / 256.0f);
    const float var = s2 * (1.0f / 256.0f) - mean * mean;
    const float rinv = rsqrtf(var + LNEPS);
    ushort_t* xp = Xh + (bT2 + T_ + t) * DIN + kg * 4;
    if (lastLayer) {
      float* op = out + ((size_t)b * T_ + t) * (DD * 4) + h * DD + kg * 4;
      const us4v zz = {0, 0, 0, 0};
      const f32x4 zf = {0.f, 0.f, 0.f, 0.f};
#pragma unroll
      for (int db = 0; db < 16; ++db) {
        f32x4 w4 = *(const f32x4*)&nw[db * 16 + kg * 4];
        f32x4 b4 = *(const f32x4*)&nb[db * 16 + kg * 4];
        f32x4 y;
#pragma unroll
        for (int rr = 0; rr < 4; ++rr) y[rr] = (acc_o[db][rr] - mean) * rinv * w4[rr] + b4[rr];
        *(f32x4*)(op + db * 16) = y;
        *(f32x4*)(cp + db * 16) = zf;
        *(us4v*)(xp + db * 16) = zz;
      }
    } else {
#pragma unroll
      for (int db = 0; db < 16; ++db) {
        f32x4 w4 = *(const f32x4*)&nw[db * 16 + kg * 4];
        f32x4 b4 = *(const f32x4*)&nb[db * 16 + kg * 4];
        f32x4 y;
        us4v yh;
#pragma unroll
        for (int rr = 0; rr < 4; ++rr) {
          y[rr] = (acc_o[db][rr] - mean) * rinv * w4[rr] + b4[rr];
          yh[rr] = f2bf(y[rr]);
        }
        *(f32x4*)(cp + db * 16) = y;
        *(us4v*)(xp + db * 16) = yh;
      }
    }
  }

  // ---------- row0 mean-V fold (4 lightest top chunks) ----------
  if (!hb && tc < 4) {
    const int col = tc * 64 + (tid & 63);
    const int half = tid >> 6;
    float s = 0.f;
    for (int tl = half * 32; tl < half * 32 + 32; ++tl) {
      const ushort_t* vp = VTt + ((size_t)(b * 64 + tl)) * 8192 + col * 32;
#pragma unroll
      for (int j = 0; j < 32; j += 8) {
        uint4 v = *(const uint4*)(vp + j);
        const uint_t vs[4] = {v.x, v.y, v.z, v.w};
#pragma unroll
        for (int q = 0; q < 4; ++q) {
          s += __uint_as_float(vs[q] << 16);
          s += __uint_as_float(vs[q] & 0xffff0000u);
        }
      }
    }
    red[half * 64 + (tid & 63)] = s;
    __syncthreads();
    if (tid < 64)
      Xh[bT2 * DIN + tc * 64 + tid] =
          f2bf((red[tid] + red[64 + tid]) * (1.0f / 2048.0f));
  }
}

extern "C" void kernel_launch(void* const* d_in, const int* in_sizes, int n_in,
                              void* d_out, int out_size, void* d_ws, size_t ws_size,
                              hipStream_t stream) {
  const float* ev = (const float*)d_in[0];
  const float* tm = (const float*)d_in[1];
  const float* Wt = (const float*)d_in[3];
  const float* bt = (const float*)d_in[4];
  const float* Wq = (const float*)d_in[5];
  const float* bq = (const float*)d_in[6];
  const float* Wk = (const float*)d_in[7];
  const float* bk = (const float*)d_in[8];
  const float* Wv = (const float*)d_in[9];
  const float* bv = (const float*)d_in[10];
  const float* nw = (const float*)d_in[11];
  const float* nb = (const float*)d_in[12];
  float* out = (float*)d_out;

  char* p = (char*)d_ws;
  ushort_t* Xh  = (ushort_t*)p; p += (size_t)BB * T2 * DIN * 2;   // 8.39 MB
  ushort_t* Qh  = (ushort_t*)p; p += (size_t)BB * T2 * DD * 2;    // 4.19 MB
  ushort_t* Kh  = (ushort_t*)p; p += (size_t)BB * T2 * DD * 2;
  ushort_t* VTt = (ushort_t*)p; p += (size_t)BB * T2 * DD * 2;    // pi32-tiled V
  float* Cur    = (float*)p;    p += (size_t)BB * T_ * DD * 4;    // 4.19 MB
  ushort_t* WT  = (ushort_t*)p; p += (size_t)36 * DD * DIN * 2;   // 9.44 MB
  float* PartO  = (float*)p;    p += (size_t)256 * 5 * 32 * 256 * 4;  // 41.9 MB
  float* PartML = (float*)p;                                          // 0.33 MB

  k_init<<<BB * T_, 256, 0, stream>>>(ev, tm, Wt, bt, Xh, Cur);
  k_transW<<<dim3(36, 32), 256, 0, stream>>>(Wq, Wk, Wv, WT);

  for (int h = 0; h < 4; ++h) {
    for (int l = 0; l < 3; ++l) {
      const int hl = h * 3 + l;
      const size_t boff = (size_t)hl * DD;
      k_qkv<<<dim3(64, 2, 3), 256, 0, stream>>>(Xh, WT, bq + boff, bk + boff, bv + boff,
                                                Qh, Kh, VTt, hl);
      k_fpart<<<1280, 128, 0, stream>>>(Qh, Kh, VTt, PartO, PartML);
      k_merge<<<256, 128, 0, stream>>>(VTt, Cur, Xh, out, nw, nb,
                                       PartO, PartML, (l == 2) ? 1 : 0, h);
    }
  }
}

// Round 16
// 755.723 us; speedup vs baseline: 1.7116x; 1.0371x over previous
//
#include <hip/hip_runtime.h>

typedef __attribute__((ext_vector_type(8))) short short8;
typedef __attribute__((ext_vector_type(4))) float f32x4;
typedef __attribute__((ext_vector_type(4))) unsigned short us4v;
typedef unsigned short ushort_t;
typedef unsigned int uint_t;

#define BB 4
#define T_ 1024
#define T2 2048
#define DD 256
#define DIN 512
#define NMARK 64
#define LNEPS 1e-5f
#define KDIV (-0.035977892078032f)
#define SEGL 8

__device__ __forceinline__ ushort_t f2bf(float f) {
  unsigned int u = __float_as_uint(f);
  unsigned int r = (u + 0x7fffu + ((u >> 16) & 1u)) >> 16;
  return (ushort_t)r;
}
__device__ __forceinline__ uint_t pack2(float a, float b) {
  return (uint_t)f2bf(a) | ((uint_t)f2bf(b) << 16);
}
__device__ __forceinline__ uint_t cvtpk(float lo, float hi) {
  uint_t r;
  asm("v_cvt_pk_bf16_f32 %0, %1, %2" : "=v"(r) : "v"(lo), "v"(hi));
  return r;
}

typedef const __attribute__((address_space(1))) unsigned int* as1cu32;
typedef __attribute__((address_space(3))) unsigned int* as3u32;
__device__ __forceinline__ void async_copy16(const void* g, void* l) {
  __builtin_amdgcn_global_load_lds((as1cu32)g, (as3u32)l, 16, 0, 0);
}

// ---------- init: type/time embeddings -> Xh (bf16), Cur = 0 ----------
__global__ __launch_bounds__(256) void k_init(const float* __restrict__ ev,
                                              const float* __restrict__ tm,
                                              const float* __restrict__ Wt,
                                              const float* __restrict__ bt,
                                              ushort_t* __restrict__ Xh,
                                              float* __restrict__ Cur) {
  const int btq = blockIdx.x;
  const int b = btq >> 10;
  const int t = btq & 1023;
  const int d = threadIdx.x;
  __shared__ float evs[NMARK];
  if (d < NMARK) evs[d] = ev[(size_t)btq * NMARK + d];
  __syncthreads();
  float s = bt[d];
#pragma unroll
  for (int m = 0; m < NMARK; ++m) s += evs[m] * Wt[m * DD + d];
  const float te_type = tanhf(s);
  const float tv = tm[btq];
  const int i = d >> 1;
  const float dv = expf((float)(2 * i) * KDIV);
  const float ang = tv * dv;
  const float te_time = (d & 1) ? cosf(ang) : sinf(ang);
  ushort_t* Xb = Xh + (size_t)b * T2 * DIN;
  const ushort_t tt = f2bf(te_time);
  Xb[(size_t)t * DIN + d] = f2bf(te_type);
  Xb[(size_t)t * DIN + DD + d] = tt;
  Xb[(size_t)(T_ + t) * DIN + d] = 0;
  Xb[(size_t)(T_ + t) * DIN + DD + d] = tt;
  Cur[((size_t)b * T_ + t) * DD + d] = 0.0f;
}

// ---------- weight transpose: W[hl][k][n] f32 -> WT[mat][n][k] bf16 ----------
__global__ __launch_bounds__(256) void k_transW(const float* __restrict__ Wq,
                                                const float* __restrict__ Wk,
                                                const float* __restrict__ Wv,
                                                ushort_t* __restrict__ WT) {
  const int mi = blockIdx.x;
  const int wsel = mi / 12, hl = mi % 12;
  const float* W = ((wsel == 0) ? Wq : (wsel == 1) ? Wk : Wv) + (size_t)hl * DIN * DD;
  const int t = blockIdx.y;
  const int k0 = (t >> 2) * 64, n0 = (t & 3) * 64;
  __shared__ float Ts[64][65];
  const int tid = threadIdx.x;
#pragma unroll
  for (int i = 0; i < 16; ++i) {
    const int idx = tid + i * 256;
    const int r = idx >> 6, c = idx & 63;
    Ts[r][c] = W[(size_t)(k0 + r) * DD + n0 + c];
  }
  __syncthreads();
  ushort_t* D = WT + (size_t)mi * DD * DIN;
#pragma unroll
  for (int i = 0; i < 16; ++i) {
    const int idx = tid + i * 256;
    const int rn = idx >> 6, ck = idx & 63;
    D[(size_t)(n0 + rn) * DIN + k0 + ck] = f2bf(Ts[ck][rn]);
  }
}

// ---------- QKV GEMM; V written pi32-permuted into 32-wide TILES ----------
__global__ __launch_bounds__(256) void k_qkv(const ushort_t* __restrict__ Xh,
                                             const ushort_t* __restrict__ WT,
                                             const float* __restrict__ bq,
                                             const float* __restrict__ bk,
                                             const float* __restrict__ bv,
                                             ushort_t* __restrict__ Qh,
                                             ushort_t* __restrict__ Kh,
                                             ushort_t* __restrict__ VTt,
                                             int hl) {
  const int m0 = blockIdx.x * 128;
  const int n0 = blockIdx.y * 128;
  const int wsel = blockIdx.z;
  const ushort_t* Bt = WT + ((size_t)(wsel * 12 + hl)) * DD * DIN + (size_t)n0 * DIN;
  const float* bias = (wsel == 0) ? bq : (wsel == 1) ? bk : bv;

  __shared__ ushort_t As[128 * 64];
  __shared__ ushort_t Bs[128 * 64];
  const int tid = threadIdx.x;
  const int w = tid >> 6, lane = tid & 63;
  const int wr = w >> 1, wc = w & 1;
  const int lr = lane & 15, kg = lane >> 4;

  f32x4 acc[4][4];
  const f32x4 z4 = {0.f, 0.f, 0.f, 0.f};
#pragma unroll
  for (int a = 0; a < 4; ++a)
#pragma unroll
    for (int c = 0; c < 4; ++c) acc[a][c] = z4;

  for (int k0 = 0; k0 < DIN; k0 += 64) {
#pragma unroll
    for (int i = 0; i < 4; ++i) {
      const int idx = tid + i * 256;
      const int row = idx >> 3, ch = idx & 7;
      const int db = row * 128 + ((ch * 16) ^ ((row & 7) << 4));
      uint4 va = *(const uint4*)&Xh[(size_t)(m0 + row) * DIN + k0 + ch * 8];
      *(uint4*)((char*)As + db) = va;
      uint4 vb = *(const uint4*)&Bt[(size_t)row * DIN + k0 + ch * 8];
      *(uint4*)((char*)Bs + db) = vb;
    }
    __syncthreads();
#pragma unroll
    for (int kk = 0; kk < 2; ++kk) {
      short8 af[4], bfr[4];
      const int cb = kk * 64 + kg * 16;
#pragma unroll
      for (int mi = 0; mi < 4; ++mi) {
        const int row = wr * 64 + mi * 16 + lr;
        af[mi] = *(const short8*)((const char*)As + row * 128 + (cb ^ ((row & 7) << 4)));
      }
#pragma unroll
      for (int ni = 0; ni < 4; ++ni) {
        const int row = wc * 64 + ni * 16 + lr;
        bfr[ni] = *(const short8*)((const char*)Bs + row * 128 + (cb ^ ((row & 7) << 4)));
      }
#pragma unroll
      for (int mi = 0; mi < 4; ++mi)
#pragma unroll
        for (int ni = 0; ni < 4; ++ni)
          acc[mi][ni] = __builtin_amdgcn_mfma_f32_16x16x32_bf16(af[mi], bfr[ni], acc[mi][ni], 0, 0, 0);
    }
    __syncthreads();
  }

  if (wsel < 2) {
    ushort_t* C = (wsel == 0) ? Qh : Kh;
#pragma unroll
    for (int mi = 0; mi < 4; ++mi)
#pragma unroll
      for (int ni = 0; ni < 4; ++ni) {
        const int col = n0 + wc * 64 + ni * 16 + lr;
        const float bcol = bias[col];
        const int rbase = m0 + wr * 64 + mi * 16 + kg * 4;
#pragma unroll
        for (int r = 0; r < 4; ++r)
          C[(size_t)(rbase + r) * DD + col] = f2bf(acc[mi][ni][r] + bcol);
      }
  } else {
    const int b2 = m0 >> 11;
    const int t0q = m0 & 2047;
#pragma unroll
    for (int mi = 0; mi < 4; ++mi)
#pragma unroll
      for (int ni = 0; ni < 4; ++ni) {
        const int col = n0 + wc * 64 + ni * 16 + lr;
        const float bcol = bias[col];
        const int t32 = (t0q >> 5) + wr * 2 + (mi >> 1);
        const int jloc = kg * 8 + (mi & 1) * 4;
        uint2 pk;
        pk.x = pack2(acc[mi][ni][0] + bcol, acc[mi][ni][1] + bcol);
        pk.y = pack2(acc[mi][ni][2] + bcol, acc[mi][ni][3] + bcol);
        *(uint2*)(VTt + ((size_t)(b2 * 64 + t32)) * (DD * 32) + col * 32 + jloc) = pk;
      }
  }
}

// ---------- flash partial: both halves share staged tiles ----------
// grid 640 = 5 seg-slots x (32 chunks x 4 batches); dead slots exit.
// Block: 4 waves = {top,bottom} x {rows 0-15,16-31} of chunk tc (64 q-rows).
// Tile sequence [0..tc, diag]; top waves skip the diag tile's compute.
// Single-seg chunks (tc<=6) do the epilogue (+row0 fold) directly.
__global__ __launch_bounds__(256, 2) void k_fpart(const ushort_t* __restrict__ Qh,
                                                  const ushort_t* __restrict__ Kh,
                                                  const ushort_t* __restrict__ VTt,
                                                  float* __restrict__ Cur,
                                                  ushort_t* __restrict__ Xh,
                                                  float* __restrict__ out,
                                                  const float* __restrict__ nw,
                                                  const float* __restrict__ nb,
                                                  float* __restrict__ PartO,
                                                  float* __restrict__ PartML,
                                                  int lastLayer, int h) {
  __shared__ char lds[66560];   // K dbuf 2x16KB | V dbuf 2x16KB @32768 | red @65536
  const int tid = threadIdx.x;
  const int bx = blockIdx.x;
  const int seg = bx >> 7;
  const int rem = bx & 127;
  const int b = rem & 3;
  const int tc = 31 - (rem >> 2);       // heavy chunks first
  const int nt = tc + 2;                // causal 0..tc + diag
  const int nseg = (nt + SEGL - 1) / SEGL;
  if (seg >= nseg) return;
  const int kt0 = seg * SEGL;
  const int klen = (nt - kt0 < SEGL) ? (nt - kt0) : SEGL;
  const int dt = 32 + tc;

  const int w = tid >> 6, lane = tid & 63;
  const int kg = lane >> 4, lr = lane & 15;
  const int half = w >> 1;
  const int tq = (w & 1) * 16 + lr;     // 0..31 within chunk
  const int t = tc * 32 + tq;
  const int r0 = (half ? T_ : 0) + t;
  const size_t bT2 = (size_t)b * T2;

  short8 qf[8];
  {
    const ushort_t* qb = Qh + (bT2 + r0) * DD + kg * 8;
#pragma unroll
    for (int kk = 0; kk < 8; ++kk) qf[kk] = *(const short8*)(qb + kk * 32);
  }

  const f32x4 z4 = {0.f, 0.f, 0.f, 0.f};
  f32x4 acc_o[16];
#pragma unroll
  for (int db = 0; db < 16; ++db) acc_o[db] = z4;
  float m_run = -1e30f, l_run = 0.f;

  // 4 waves co-stage one 32KB tile: wave w issues chunks c = w*4..w*4+3 (K+V)
#define STAGE(BUF, TILE)                                                                  \
  {                                                                                       \
    const int _t = (TILE);                                                                \
    const char* Vt = (const char*)VTt + ((size_t)(b * 64 + _t)) * 16384;                  \
    _Pragma("unroll") for (int s = 0; s < 4; ++s) {                                       \
      const int c = w * 4 + s;                                                            \
      const int row2 = (c << 1) | (lane >> 5);                                            \
      const int cc2 = lane & 31;                                                          \
      async_copy16((const char*)Kh + ((bT2 + _t * 32 + row2) * DD) * 2 +                  \
                       ((cc2 * 16) ^ ((row2 & 7) << 4)),                                  \
                   lds + (BUF) * 16384 + c * 1024);                                       \
      async_copy16(Vt + c * 1024 + lane * 16,                                             \
                   lds + 32768 + (BUF) * 16384 + c * 1024);                               \
    }                                                                                     \
  }
#define TILEOF(KT) (((KT) <= tc) ? (KT) : dt)

  STAGE(0, TILEOF(kt0));

  union U8 { uint4 u; short8 s; };

  for (int ktl = 0; ktl < klen; ++ktl) {
    const int kt = kt0 + ktl;
    const int tile = TILEOF(kt);
    const bool isDiag = (kt > tc);

    if (ktl + 1 < klen) {
      STAGE((ktl + 1) & 1, TILEOF(kt + 1));
      asm volatile("s_waitcnt vmcnt(8)" ::: "memory");
    } else {
      asm volatile("s_waitcnt vmcnt(0)" ::: "memory");
    }
    __builtin_amdgcn_s_barrier();
    asm volatile("" ::: "memory");

    if (!(isDiag && half == 0)) {
      const char* KsC = lds + (ktl & 1) * 16384;
      const char* VsC = lds + 32768 + (ktl & 1) * 16384;

      // QK^T (swapped): S^T[j = tile*32 + jb*16 + kg*4 + r][q = lr]
      f32x4 sa[2];
#pragma unroll
      for (int jb = 0; jb < 2; ++jb) {
        sa[jb] = z4;
        const int rowj = jb * 16 + lr;
        const int base = rowj * 512;
        const int swj = (rowj & 7) << 4;
#pragma unroll
        for (int kk = 0; kk < 8; ++kk) {
          short8 kf = *(const short8*)(KsC + base + ((kk * 64 + kg * 16) ^ swj));
          sa[jb] = __builtin_amdgcn_mfma_f32_16x16x32_bf16(kf, qf[kk], sa[jb], 0, 0, 0);
        }
      }

      // mask + scale + online softmax with defer-max
      float sv[8];
      float tmax = -1e30f;
#pragma unroll
      for (int jb = 0; jb < 2; ++jb)
#pragma unroll
        for (int rr = 0; rr < 4; ++rr) {
          const int jl = jb * 16 + kg * 4 + rr;
          const bool valid = isDiag ? (jl == tq) : ((tile * 32 + jl) < t);
          const float x = valid ? sa[jb][rr] * 0.0625f : -1e30f;
          sv[jb * 4 + rr] = x;
          tmax = fmaxf(tmax, x);
        }
      tmax = fmaxf(tmax, __shfl_xor(tmax, 16, 64));
      tmax = fmaxf(tmax, __shfl_xor(tmax, 32, 64));
      if (tmax > m_run + 8.0f) {
        const float fac = __expf(m_run - tmax);
        m_run = tmax;
        l_run *= fac;
#pragma unroll
        for (int db = 0; db < 16; ++db) acc_o[db] *= fac;
      }
      float p[8];
      float psum = 0.f;
#pragma unroll
      for (int e = 0; e < 8; ++e) {
        const float pe = (sv[e] > -1e29f) ? __expf(sv[e] - m_run) : 0.0f;
        p[e] = pe;
        psum += pe;
      }
      psum += __shfl_xor(psum, 16, 64);
      psum += __shfl_xor(psum, 32, 64);
      l_run += psum;

      U8 pf;
      pf.u.x = cvtpk(p[0], p[1]);
      pf.u.y = cvtpk(p[2], p[3]);
      pf.u.z = cvtpk(p[4], p[5]);
      pf.u.w = cvtpk(p[6], p[7]);

      // PV: O^T += V^T * P^T (K=32), V from LDS pi32 layout
#pragma unroll
      for (int db = 0; db < 16; ++db) {
        U8 vf;
        vf.u = *(const uint4*)(VsC + (db * 16 + lr) * 64 + kg * 16);
        acc_o[db] = __builtin_amdgcn_mfma_f32_16x16x32_bf16(vf.s, pf.s, acc_o[db], 0, 0, 0);
      }
    }

    __builtin_amdgcn_s_barrier();
    asm volatile("" ::: "memory");
  }
#undef STAGE
#undef TILEOF

  if (nseg > 1) {
    // ---------- write partial (64-row slot) ----------
    const int slot = (b * 32 + tc) * 5 + seg;
    const int row = half * 32 + tq;
    float* pml = PartML + slot * 128;
    if (kg == 0) { pml[row] = m_run; pml[64 + row] = l_run; }
    float* po = PartO + ((size_t)slot) * (64 * 256) + row * 256 + kg * 4;
#pragma unroll
    for (int db = 0; db < 16; ++db) *(f32x4*)(po + db * 16) = acc_o[db];
    return;
  }

  // ---------- single-segment: direct epilogue ----------
  const float oinv = 1.0f / l_run;   // t==0 (top): l==0 -> store skipped

  if (!half) {
    if (t != 0) {
      ushort_t* xp = Xh + (bT2 + t) * DIN + kg * 4;
#pragma unroll
      for (int db = 0; db < 16; ++db) {
        us4v o;
#pragma unroll
        for (int rr = 0; rr < 4; ++rr) o[rr] = f2bf(acc_o[db][rr] * oinv);
        *(us4v*)(xp + db * 16) = o;
      }
    }
  } else {
    float* cp = Cur + ((size_t)b * T_ + t) * DD + kg * 4;
    float s1 = 0.f, s2 = 0.f;
#pragma unroll
    for (int db = 0; db < 16; ++db) {
      f32x4 c4 = *(const f32x4*)(cp + db * 16);
#pragma unroll
      for (int rr = 0; rr < 4; ++rr) {
        const float x = tanhf(acc_o[db][rr] * oinv) + c4[rr];
        acc_o[db][rr] = x;
        s1 += x;
        s2 += x * x;
      }
    }
    s1 += __shfl_xor(s1, 16, 64); s1 += __shfl_xor(s1, 32, 64);
    s2 += __shfl_xor(s2, 16, 64); s2 += __shfl_xor(s2, 32, 64);
    const float mean = s1 * (1.0f / 256.0f);
    const float var = s2 * (1.0f / 256.0f) - mean * mean;
    const float rinv = rsqrtf(var + LNEPS);
    ushort_t* xp = Xh + (bT2 + T_ + t) * DIN + kg * 4;
    if (lastLayer) {
      float* op = out + ((size_t)b * T_ + t) * (DD * 4) + h * DD + kg * 4;
      const us4v zz = {0, 0, 0, 0};
      const f32x4 zf = {0.f, 0.f, 0.f, 0.f};
#pragma unroll
      for (int db = 0; db < 16; ++db) {
        f32x4 w4 = *(const f32x4*)&nw[db * 16 + kg * 4];
        f32x4 b4 = *(const f32x4*)&nb[db * 16 + kg * 4];
        f32x4 y;
#pragma unroll
        for (int rr = 0; rr < 4; ++rr) y[rr] = (acc_o[db][rr] - mean) * rinv * w4[rr] + b4[rr];
        *(f32x4*)(op + db * 16) = y;
        *(f32x4*)(cp + db * 16) = zf;
        *(us4v*)(xp + db * 16) = zz;
      }
    } else {
#pragma unroll
      for (int db = 0; db < 16; ++db) {
        f32x4 w4 = *(const f32x4*)&nw[db * 16 + kg * 4];
        f32x4 b4 = *(const f32x4*)&nb[db * 16 + kg * 4];
        f32x4 y;
        us4v yh;
#pragma unroll
        for (int rr = 0; rr < 4; ++rr) {
          y[rr] = (acc_o[db][rr] - mean) * rinv * w4[rr] + b4[rr];
          yh[rr] = f2bf(y[rr]);
        }
        *(f32x4*)(cp + db * 16) = y;
        *(us4v*)(xp + db * 16) = yh;
      }
    }
  }

  // ---------- row0 mean-V fold (tc<4; all single-seg) ----------
  if (tc < 4) {
    __syncthreads();
    float* red = (float*)(lds + 65536);
    const int col = tc * 64 + (tid & 63);
    const int q4 = tid >> 6;
    float s = 0.f;
    for (int tl = q4 * 16; tl < q4 * 16 + 16; ++tl) {
      const ushort_t* vp = VTt + ((size_t)(b * 64 + tl)) * 8192 + col * 32;
#pragma unroll
      for (int j = 0; j < 32; j += 8) {
        uint4 v = *(const uint4*)(vp + j);
        const uint_t vs[4] = {v.x, v.y, v.z, v.w};
#pragma unroll
        for (int q = 0; q < 4; ++q) {
          s += __uint_as_float(vs[q] << 16);
          s += __uint_as_float(vs[q] & 0xffff0000u);
        }
      }
    }
    red[q4 * 64 + (tid & 63)] = s;
    __syncthreads();
    if (tid < 64)
      Xh[bT2 * DIN + tc * 64 + tid] =
          f2bf((red[tid] + red[64 + tid] + red[128 + tid] + red[192 + tid]) * (1.0f / 2048.0f));
  }
}

// ---------- merge + epilogue for multi-seg chunks (tc>=7): grid 100 x 256 ----------
__global__ __launch_bounds__(256) void k_merge(float* __restrict__ Cur,
                                               ushort_t* __restrict__ Xh,
                                               float* __restrict__ out,
                                               const float* __restrict__ nw,
                                               const float* __restrict__ nb,
                                               const float* __restrict__ PartO,
                                               const float* __restrict__ PartML,
                                               int lastLayer, int h) {
  const int tid = threadIdx.x;
  const int bx = blockIdx.x;
  const int b = bx & 3;
  const int tc = 7 + (bx >> 2);
  const int nt = tc + 2;
  const int nseg = (nt + SEGL - 1) / SEGL;
  const int slot0 = (b * 32 + tc) * 5;

  const int w = tid >> 6, lane = tid & 63;
  const int kg = lane >> 4, lr = lane & 15;
  const int half = w >> 1;
  const int tq = (w & 1) * 16 + lr;
  const int t = tc * 32 + tq;
  const int row = half * 32 + tq;
  const size_t bT2 = (size_t)b * T2;
  const f32x4 z4 = {0.f, 0.f, 0.f, 0.f};

  // merge segments (fixed order -> deterministic)
  float mstar = -1e30f;
  for (int s = 0; s < nseg; ++s)
    mstar = fmaxf(mstar, PartML[(slot0 + s) * 128 + row]);
  float l_run = 0.f;
  f32x4 acc_o[16];
#pragma unroll
  for (int db = 0; db < 16; ++db) acc_o[db] = z4;
  for (int s = 0; s < nseg; ++s) {
    const float* pml = PartML + (slot0 + s) * 128;
    const float f = __expf(pml[row] - mstar);
    l_run += f * pml[64 + row];
    const float* po = PartO + ((size_t)(slot0 + s)) * (64 * 256) + row * 256 + kg * 4;
#pragma unroll
    for (int db = 0; db < 16; ++db) {
      f32x4 v = *(const f32x4*)(po + db * 16);
#pragma unroll
      for (int q = 0; q < 4; ++q) acc_o[db][q] += f * v[q];
    }
  }

  const float oinv = 1.0f / l_run;

  if (!half) {
    ushort_t* xp = Xh + (bT2 + t) * DIN + kg * 4;
#pragma unroll
    for (int db = 0; db < 16; ++db) {
      us4v o;
#pragma unroll
      for (int rr = 0; rr < 4; ++rr) o[rr] = f2bf(acc_o[db][rr] * oinv);
      *(us4v*)(xp + db * 16) = o;
    }
  } else {
    float* cp = Cur + ((size_t)b * T_ + t) * DD + kg * 4;
    float s1 = 0.f, s2 = 0.f;
#pragma unroll
    for (int db = 0; db < 16; ++db) {
      f32x4 c4 = *(const f32x4*)(cp + db * 16);
#pragma unroll
      for (int rr = 0; rr < 4; ++rr) {
        const float x = tanhf(acc_o[db][rr] * oinv) + c4[rr];
        acc_o[db][rr] = x;
        s1 += x;
        s2 += x * x;
      }
    }
    s1 += __shfl_xor(s1, 16, 64); s1 += __shfl_xor(s1, 32, 64);
    s2 += __shfl_xor(s2, 16, 64); s2 += __shfl_xor(s2, 32, 64);
    const float mean = s1 * (1.0f / 256.0f);
    const float var = s2 * (1.0f / 256.0f) - mean * mean;
    const float rinv = rsqrtf(var + LNEPS);
    ushort_t* xp = Xh + (bT2 + T_ + t) * DIN + kg * 4;
    if (lastLayer) {
      float* op = out + ((size_t)b * T_ + t) * (DD * 4) + h * DD + kg * 4;
      const us4v zz = {0, 0, 0, 0};
      const f32x4 zf = {0.f, 0.f, 0.f, 0.f};
#pragma unroll
      for (int db = 0; db < 16; ++db) {
        f32x4 w4 = *(const f32x4*)&nw[db * 16 + kg * 4];
        f32x4 b4 = *(const f32x4*)&nb[db * 16 + kg * 4];
        f32x4 y;
#pragma unroll
        for (int rr = 0; rr < 4; ++rr) y[rr] = (acc_o[db][rr] - mean) * rinv * w4[rr] + b4[rr];
        *(f32x4*)(op + db * 16) = y;
        *(f32x4*)(cp + db * 16) = zf;
        *(us4v*)(xp + db * 16) = zz;
      }
    } else {
#pragma unroll
      for (int db = 0; db < 16; ++db) {
        f32x4 w4 = *(const f32x4*)&nw[db * 16 + kg * 4];
        f32x4 b4 = *(const f32x4*)&nb[db * 16 + kg * 4];
        f32x4 y;
        us4v yh;
#pragma unroll
        for (int rr = 0; rr < 4; ++rr) {
          y[rr] = (acc_o[db][rr] - mean) * rinv * w4[rr] + b4[rr];
          yh[rr] = f2bf(y[rr]);
        }
        *(f32x4*)(cp + db * 16) = y;
        *(us4v*)(xp + db * 16) = yh;
      }
    }
  }
}

extern "C" void kernel_launch(void* const* d_in, const int* in_sizes, int n_in,
                              void* d_out, int out_size, void* d_ws, size_t ws_size,
                              hipStream_t stream) {
  const float* ev = (const float*)d_in[0];
  const float* tm = (const float*)d_in[1];
  const float* Wt = (const float*)d_in[3];
  const float* bt = (const float*)d_in[4];
  const float* Wq = (const float*)d_in[5];
  const float* bq = (const float*)d_in[6];
  const float* Wk = (const float*)d_in[7];
  const float* bk = (const float*)d_in[8];
  const float* Wv = (const float*)d_in[9];
  const float* bv = (const float*)d_in[10];
  const float* nw = (const float*)d_in[11];
  const float* nb = (const float*)d_in[12];
  float* out = (float*)d_out;

  char* p = (char*)d_ws;
  ushort_t* Xh  = (ushort_t*)p; p += (size_t)BB * T2 * DIN * 2;   // 8.39 MB
  ushort_t* Qh  = (ushort_t*)p; p += (size_t)BB * T2 * DD * 2;    // 4.19 MB
  ushort_t* Kh  = (ushort_t*)p; p += (size_t)BB * T2 * DD * 2;
  ushort_t* VTt = (ushort_t*)p; p += (size_t)BB * T2 * DD * 2;    // pi32-tiled V
  float* Cur    = (float*)p;    p += (size_t)BB * T_ * DD * 4;    // 4.19 MB
  ushort_t* WT  = (ushort_t*)p; p += (size_t)36 * DD * DIN * 2;   // 9.44 MB
  float* PartO  = (float*)p;    p += (size_t)640 * 64 * 256 * 4;  // 41.9 MB
  float* PartML = (float*)p;                                      // 0.33 MB

  k_init<<<BB * T_, 256, 0, stream>>>(ev, tm, Wt, bt, Xh, Cur);
  k_transW<<<dim3(36, 32), 256, 0, stream>>>(Wq, Wk, Wv, WT);

  for (int h = 0; h < 4; ++h) {
    for (int l = 0; l < 3; ++l) {
      const int hl = h * 3 + l;
      const size_t boff = (size_t)hl * DD;
      k_qkv<<<dim3(64, 2, 3), 256, 0, stream>>>(Xh, WT, bq + boff, bk + boff, bv + boff,
                                                Qh, Kh, VTt, hl);
      k_fpart<<<640, 256, 0, stream>>>(Qh, Kh, VTt, Cur, Xh, out, nw, nb,
                                       PartO, PartML, (l == 2) ? 1 : 0, h);
      k_merge<<<100, 256, 0, stream>>>(Cur, Xh, out, nw, nb,
                                       PartO, PartML, (l == 2) ? 1 : 0, h);
    }
  }
}